// Round 4
// baseline (4502.834 us; speedup 1.0000x reference)
//
#include <hip/hip_runtime.h>
#include <stdint.h>

// LSTM forward, B=128 T=512 F=256 H=512, Keras gate order i,f,g,o.
//  kernel lstm_xz : xz[B*T,2048] = x @ kernel + bias  (split-bf16 MFMA, fp16 output)
//  kernel lstm_rec: persistent scan. R4: BARRIER-FREE inner loop.
//    - hbuf slot layout is row-major [16][512] bf16 == exactly the MFMA A-fragment
//      layout (lane: row cB, k-slice kk*32+kgrp*8 = 16B chunk). So the LDS restage
//      (ds_write x4 + 2 syncthreads + ds_read_b128 x16) is DELETED: each lane fetches
//      its 16 A-fragments directly with pipelined global_load_dwordx4 sc0 sc1, and the
//      sentinel-poll and A-fetch are the SAME loads (retry until no 0xFFFFFFFF dword).
//    - No __syncthreads in the loop: 4 waves/block fully decoupled; a poll retry
//      stalls only its own wave. Costs 4x redundant LLC reads (64KB/block/step,
//      hbuf LLC-resident -> no HBM delta); buys latency + removes bank conflicts.
//    - Sentinel reset now per-wave (wave resets its OWN 8-col slice of slot t-2);
//      ordering proof unchanged: reset drains at that wave's next poll vmcnt(0),
//      before that wave's h(t+1) signal; consumer pass on slot t+1 => reset durable.
// ws layout: [0, 256MB) xz fp16 | hbuf 8 groups x 4 slots x 16 rows x 256 dwords (512KB)

#define Bb 128
#define Tt 512
#define Ff 256
#define Hh 512
#define G4 2048
#define SENT 0xFFFFFFFFu

typedef __attribute__((ext_vector_type(8))) short short8;
typedef __attribute__((ext_vector_type(4))) float floatx4;
typedef __attribute__((ext_vector_type(4))) unsigned int uint4v;

__device__ __forceinline__ unsigned short f2bf(float f) {
    unsigned u = __float_as_uint(f);
    return (unsigned short)((u + 0x7FFFu + ((u >> 16) & 1u)) >> 16);
}
__device__ __forceinline__ float bf2f(unsigned short h) {
    return __uint_as_float(((unsigned)h) << 16);
}
__device__ __forceinline__ float sigm(float x) { return 1.f / (1.f + __expf(-x)); }
__device__ __forceinline__ float tanh_f(float x) {
    float e = __expf(-2.f * fabsf(x));
    return copysignf((1.f - e) / (1.f + e), x);
}

// ---------------------------------------------------------------------------
// Kernel A: xz = x @ w + bias, stored fp16. Split-bf16 (x=hi+lo) for accuracy.
// 128x128 tile / block, BK=32 (orig k), K=256. Grid 8192 blocks. (unchanged)
// ---------------------------------------------------------------------------
__global__ __launch_bounds__(256, 2) void lstm_xz(
    const float* __restrict__ x, const float* __restrict__ w,
    const float* __restrict__ bias, _Float16* __restrict__ xzh)
{
    __shared__ unsigned short Ahi[128 * 40];
    __shared__ unsigned short Alo[128 * 40];
    __shared__ unsigned short Wt [128 * 40];

    const int tid = threadIdx.x;
    int idx = blockIdx.x;
    int xcd = idx & 7;
    int chunk = idx >> 3;
    int msup = chunk >> 7;
    int s = chunk & 127;
    int nt = s >> 3;
    int mi0 = s & 7;
    int mt = xcd * 64 + msup * 8 + mi0;
    const int m0 = mt << 7;
    const int n0 = nt << 7;

    const int lane = tid & 63;
    const int wv = tid >> 6;
    const int wm = wv >> 1, wn = wv & 1;
    const int cB = lane & 15, kgrp = lane >> 4;

    floatx4 acc[4][4];
#pragma unroll
    for (int i = 0; i < 4; ++i)
#pragma unroll
        for (int j = 0; j < 4; ++j) acc[i][j] = (floatx4){0.f, 0.f, 0.f, 0.f};

    float bv[4];
#pragma unroll
    for (int ni = 0; ni < 4; ++ni) bv[ni] = bias[n0 + wn * 64 + ni * 16 + cB];

    for (int it = 0; it < 8; ++it) {
        const int k0 = it * 32;
#pragma unroll
        for (int sw = 0; sw < 4; ++sw) {
            int e = sw * 256 + tid;
            int row = e >> 3, kq = e & 7;
            float4 v = *((const float4*)(x + (size_t)(m0 + row) * Ff + k0) + kq);
            unsigned short h0 = f2bf(v.x), h1 = f2bf(v.y), h2 = f2bf(v.z), h3 = f2bf(v.w);
            unsigned short l0 = f2bf(v.x - bf2f(h0)), l1 = f2bf(v.y - bf2f(h1));
            unsigned short l2 = f2bf(v.z - bf2f(h2)), l3 = f2bf(v.w - bf2f(h3));
            uint2 ph, pl;
            ph.x = (unsigned)h0 | ((unsigned)h1 << 16); ph.y = (unsigned)h2 | ((unsigned)h3 << 16);
            pl.x = (unsigned)l0 | ((unsigned)l1 << 16); pl.y = (unsigned)l2 | ((unsigned)l3 << 16);
            *(uint2*)(&Ahi[row * 40 + kq * 4]) = ph;
            *(uint2*)(&Alo[row * 40 + kq * 4]) = pl;
        }
#pragma unroll
        for (int sw = 0; sw < 4; ++sw) {
            int e = sw * 256 + tid;
            int kr = e >> 5, nq = e & 31;
            float4 v = *((const float4*)(w + (size_t)(k0 + kr) * G4 + n0) + nq);
            int nb = nq * 4;
            Wt[(nb + 0) * 40 + kr] = f2bf(v.x);
            Wt[(nb + 1) * 40 + kr] = f2bf(v.y);
            Wt[(nb + 2) * 40 + kr] = f2bf(v.z);
            Wt[(nb + 3) * 40 + kr] = f2bf(v.w);
        }
        __syncthreads();

        short8 bfr[4];
#pragma unroll
        for (int ni = 0; ni < 4; ++ni)
            bfr[ni] = *(const short8*)(&Wt[(wn * 64 + ni * 16 + cB) * 40 + kgrp * 8]);
#pragma unroll
        for (int mi = 0; mi < 4; ++mi) {
            short8 ah = *(const short8*)(&Ahi[(wm * 64 + mi * 16 + cB) * 40 + kgrp * 8]);
            short8 al = *(const short8*)(&Alo[(wm * 64 + mi * 16 + cB) * 40 + kgrp * 8]);
#pragma unroll
            for (int ni = 0; ni < 4; ++ni) {
                acc[mi][ni] = __builtin_amdgcn_mfma_f32_16x16x32_bf16(ah, bfr[ni], acc[mi][ni], 0, 0, 0);
                acc[mi][ni] = __builtin_amdgcn_mfma_f32_16x16x32_bf16(al, bfr[ni], acc[mi][ni], 0, 0, 0);
            }
        }
        __syncthreads();
    }
#pragma unroll
    for (int mi = 0; mi < 4; ++mi)
#pragma unroll
        for (int ni = 0; ni < 4; ++ni) {
            int rowb = m0 + wm * 64 + mi * 16 + kgrp * 4;
            int col = n0 + wn * 64 + ni * 16 + cB;
#pragma unroll
            for (int rr = 0; rr < 4; ++rr)
                xzh[(size_t)(rowb + rr) * G4 + col] = (_Float16)(acc[mi][ni][rr] + bv[ni]);
        }
}

// ---------------------------------------------------------------------------
// Kernel R: persistent scan, 128 blocks = 8 row-groups x 16 col-blocks.
// Block: 256 thr / 4 waves, NO in-loop barriers; wave w owns h cols
// [cb*32 + w*8, +8) (x 4 gates = 32 n). B-frags in registers; A-frags fetched
// directly from the hbuf slot (row-major [16][512] bf16) with sentinel-poll.
// ---------------------------------------------------------------------------
__global__ __launch_bounds__(256, 1) void lstm_rec(
    const _Float16* __restrict__ xzh, const float* __restrict__ rk,
    unsigned* __restrict__ hbuf_u, float* __restrict__ out)
{
    __shared__ unsigned short Rlds[128 * 512];   // 128 KB, staging for B-frag hoist

    const int tid = threadIdx.x;
    const int idx = blockIdx.x;
    const int rg = idx & 7;          // row group
    const int cb = idx >> 3;         // 0..15 col block
    const int b0 = rg * 16;
    const int hc0 = cb * 32;

    const int lane = tid & 63;
    const int wv = tid >> 6;
    const int cB = lane & 15, kgrp = lane >> 4;
    const int hcw = hc0 + wv * 8;    // wave's 8 h cols
    const int c7 = cB & 7;
    const int col = hcw + c7;        // this lane's h col (duplicated in lane^8)
    const bool hi = (cB & 8) != 0;

    // ---- preload R slice into LDS, bf16, XOR-swizzled: elem (n,k) at k^((n&7)*8) ----
    for (int e = tid; e < 64 * 512; e += 256) {
        int p = e & 63, k = e >> 6;
        int n0 = 2 * p;
        int loc = n0 & 31, w = n0 >> 5;
        int gate = ((loc >> 4) << 1) | ((loc >> 3) & 1);
        int gcol = gate * Hh + hc0 + w * 8 + (loc & 7);
        float2 v = *(const float2*)(rk + (size_t)k * G4 + gcol);
        Rlds[n0 * 512 + (k ^ ((n0 & 7) << 3))] = f2bf(v.x);
        Rlds[(n0 + 1) * 512 + (k ^ (((n0 + 1) & 7) << 3))] = f2bf(v.y);
    }

    // per-row running xz pointers (4), gate offset is an immediate (g*1KB)
    const unsigned* xz_u = (const unsigned*)xzh;
    const unsigned* pr[4];
#pragma unroll
    for (int r = 0; r < 4; ++r)
        pr[r] = xz_u + ((size_t)(b0 + kgrp * 4 + r) * Tt * G4 + (col & ~1)) / 2;

    float xzr[16];                            // [gate*4 + row]
#pragma unroll
    for (int g = 0; g < 4; ++g)
#pragma unroll
        for (int r = 0; r < 4; ++r) {
            unsigned v = pr[r][g * 256];
            xzr[g * 4 + r] = (float)__builtin_bit_cast(_Float16,
                (unsigned short)((col & 1) ? (v >> 16) : (v & 0xffffu)));
        }
#pragma unroll
    for (int r = 0; r < 4; ++r) pr[r] += G4 / 2;   // -> t=1

    __syncthreads();  // Rlds ready (only barrier in the kernel)

    // ---- hoist B fragments to registers: 2 n-tiles x 16 kk = 128 VGPRs ----
    short8 bf0[16], bf1[16];
    {
        const int nb = wv * 32;
        const int swz = c7 << 3;
#pragma unroll
        for (int kk = 0; kk < 16; ++kk) {
            int kb = (kk * 32 + kgrp * 8) ^ swz;
            bf0[kk] = *(const short8*)&Rlds[(nb + cB) * 512 + kb];
            bf1[kk] = *(const short8*)&Rlds[(nb + 16 + cB) * 512 + kb];
        }
    }

    float creg[4] = {0.f, 0.f, 0.f, 0.f};
    unsigned* const gbase = hbuf_u + (size_t)rg * 4 * 4096;   // 4 slots x 16x256 dwords

    for (int t = 0; t < Tt; ++t) {
        const bool last = (t == Tt - 1);

        // 1. prefetch xz(t+1): HBM latency hides under the poll round trip
        unsigned pf[16];
        if (!last) {
#pragma unroll
            for (int g = 0; g < 4; ++g)
#pragma unroll
                for (int r = 0; r < 4; ++r)
                    pf[g * 4 + r] = pr[r][g * 256];
        }

        floatx4 acc0 = (floatx4){0.f, 0.f, 0.f, 0.f};
        floatx4 acc1 = (floatx4){0.f, 0.f, 0.f, 0.f};

        if (t > 0) {
            // 2. fused poll + A-fetch: lane reads its 16 MFMA A-fragments (row cB,
            //    k-slice kk*32+kgrp*8 => dword kk*16+kgrp*4) directly from the slot;
            //    retry until no dword is sentinel. Per-lane 16 pipelined 16B loads.
            const unsigned* sp = gbase + ((t - 1) & 3) * 4096 + cB * 256 + kgrp * 4;
            uint4v A[16];
            for (;;) {
#pragma unroll
                for (int kk = 0; kk < 16; ++kk)
                    asm volatile("global_load_dwordx4 %0, %1, off sc0 sc1"
                                 : "=v"(A[kk]) : "v"(sp + kk * 16) : "memory");
                asm volatile("s_waitcnt vmcnt(0)" ::: "memory");
                __builtin_amdgcn_sched_barrier(0);
                bool bad = false;
#pragma unroll
                for (int kk = 0; kk < 16; ++kk)
                    bad = bad | (A[kk][0] == SENT) | (A[kk][1] == SENT)
                              | (A[kk][2] == SENT) | (A[kk][3] == SENT);
                if (!__any(bad)) break;
            }

            // 3. recycle slot (t-2): wave resets its OWN 8-col slice (16 rows x 4
            //    dwords, 1 dword/lane). Drained by this wave's next poll vmcnt(0)
            //    before its h(t+1) signal => consumers passing slot t+1 see it.
            if (t >= 2) {
                unsigned* rs = gbase + ((t - 2) & 3) * 4096
                             + (lane >> 2) * 256 + (hc0 >> 1) + wv * 4 + (lane & 3);
                __hip_atomic_store(rs, SENT, __ATOMIC_RELAXED, __HIP_MEMORY_SCOPE_AGENT);
            }

            // 4. GEMM: 32 MFMA, A and B both in registers. No LDS.
#pragma unroll
            for (int kk = 0; kk < 16; ++kk) {
                short8 a = __builtin_bit_cast(short8, A[kk]);
                acc0 = __builtin_amdgcn_mfma_f32_16x16x32_bf16(a, bf0[kk], acc0, 0, 0, 0);
                acc1 = __builtin_amdgcn_mfma_f32_16x16x32_bf16(a, bf1[kk], acc1, 0, 0, 0);
            }
        }
        // t==0: h = 0 -> z = xz only (acc stays 0), no fetch, no GEMM.

        // 5. elementwise, in-register. C layout: col=lane&15, row=kgrp*4+reg.
        float hv[4];
#pragma unroll
        for (int r = 0; r < 4; ++r) {
            float a0 = acc0[r], a1 = acc1[r];
            float a0x = __shfl_xor(a0, 8);
            float a1x = __shfl_xor(a1, 8);
            float zi = (hi ? a0x : a0) + xzr[0 * 4 + r];
            float zf = (hi ? a0 : a0x) + xzr[1 * 4 + r];
            float zg = (hi ? a1x : a1) + xzr[2 * 4 + r];
            float zo = (hi ? a1 : a1x) + xzr[3 * 4 + r];
            creg[r] = sigm(zf) * creg[r] + sigm(zi) * tanh_f(zg);
            hv[r] = sigm(zo) * tanh_f(creg[r]);
        }

        float hn[4];
#pragma unroll
        for (int r = 0; r < 4; ++r) hn[r] = __shfl_xor(hv[r], 1);
        const bool ew = (!hi && !(cB & 1));

        if (!last) {
            // 6. h exchange: fire-and-forget sc1 stores into slot t&3. The data IS
            //    the signal (sentinel-poll on consumer side). No vmcnt, no flag.
            unsigned* wbase = gbase + (t & 3) * 4096;
#pragma unroll
            for (int r = 0; r < 4; ++r) {
                if (ew) {
                    unsigned hp = (unsigned)f2bf(hv[r]) | ((unsigned)f2bf(hn[r]) << 16);
                    __hip_atomic_store(wbase + (kgrp * 4 + r) * 256 + (col >> 1), hp,
                                       __ATOMIC_RELAXED, __HIP_MEMORY_SCOPE_AGENT);
                }
            }
        }

        // 7. output stores (cached; off the producer->consumer chain)
#pragma unroll
        for (int r = 0; r < 4; ++r) {
            if (ew) {
                size_t b = (size_t)(b0 + kgrp * 4 + r);
                *(float2*)(out + (b * Tt + (size_t)t) * Hh + col) = make_float2(hv[r], hn[r]);
            }
        }

        if (last) {
            float* hl = out + (size_t)Bb * Tt * Hh;
            float* cl = hl + (size_t)Bb * Hh;
#pragma unroll
            for (int r = 0; r < 4; ++r) {
                float cn = __shfl_xor(creg[r], 1);
                if (ew) {
                    size_t b = (size_t)(b0 + kgrp * 4 + r);
                    *(float2*)(hl + b * Hh + col) = make_float2(hv[r], hn[r]);
                    *(float2*)(cl + b * Hh + col) = make_float2(creg[r], cn);
                }
            }
            break;
        }

        // 8. consume prefetched xz; advance row pointers
#pragma unroll
        for (int i = 0; i < 16; ++i)
            xzr[i] = (float)__builtin_bit_cast(_Float16,
                (unsigned short)((col & 1) ? (pf[i] >> 16) : (pf[i] & 0xffffu)));
#pragma unroll
        for (int r = 0; r < 4; ++r) pr[r] += G4 / 2;
    }
}

// ---------------------------------------------------------------------------
extern "C" void kernel_launch(void* const* d_in, const int* in_sizes, int n_in,
                              void* d_out, int out_size, void* d_ws, size_t ws_size,
                              hipStream_t stream) {
    (void)in_sizes; (void)n_in; (void)out_size; (void)ws_size;
    const float* x    = (const float*)d_in[0];
    const float* w    = (const float*)d_in[1];
    const float* rk   = (const float*)d_in[2];
    const float* bias = (const float*)d_in[3];
    float* out = (float*)d_out;

    char* ws = (char*)d_ws;
    const size_t XZ_BYTES   = (size_t)Bb * Tt * G4 * sizeof(_Float16);      // 268,435,456
    const size_t HBUF_BYTES = (size_t)8 * 4 * 16 * 256 * 4;                 // 524,288

    _Float16* xzh = (_Float16*)ws;
    unsigned* hbuf = (unsigned*)(ws + XZ_BYTES);

    // sentinel-init all slots (0xFF bytes -> 0xFFFFFFFF dwords)
    hipMemsetAsync(ws + XZ_BYTES, 0xFF, HBUF_BYTES, stream);

    lstm_xz<<<dim3(8192), dim3(256), 0, stream>>>(x, w, bias, xzh);
    lstm_rec<<<dim3(128), dim3(256), 0, stream>>>(xzh, rk, hbuf, out);
}

// Round 5
// 4467.037 us; speedup vs baseline: 1.0080x; 1.0080x over previous
//
#include <hip/hip_runtime.h>
#include <stdint.h>

// LSTM forward, B=128 T=512 F=256 H=512, Keras gate order i,f,g,o.
//  kernel lstm_xz : xz[B*T,2048] = x @ kernel + bias  (split-bf16 MFMA, fp16 output)
//  kernel lstm_rec: persistent scan. R5: fix R4's retry traffic amplification.
//    - R4 post-mortem: fused poll+A-fetch retried the ENTIRE 16KB/wave A-set per spin
//      through the L1-bypassing sc1 path (FETCH 184->360MB) -> TCP/LLC congestion.
//    - R5a PER-CHUNK retry + incremental consumption: chunk kk (16B/lane) == producer
//      block kk's columns. Issue all 16 chunk loads once + vmcnt(0); then per chunk:
//      if any lane sees sentinel, reload ONLY that chunk (16B); once valid -> 2 MFMAs
//      immediately. Retries cost 16B not 16KB; MFMA overlaps laggard producers.
//    - R5b 256 blocks x 2 waves (8 groups x 32 col-blocks, 16 cols each): same total
//      waves (512), spread over all 256 CUs -> per-CU TCP traffic halves; LDS 64KB.
//    - Still barrier-free in-loop; reset ordering proof unchanged (wave's reset of
//      slot t-2 drains at its own step-t+1 initial vmcnt(0), before h(t+1) signal).
// ws layout: [0, 256MB) xz fp16 | hbuf 8 groups x 4 slots x 16 rows x 256 dwords (512KB)

#define Bb 128
#define Tt 512
#define Ff 256
#define Hh 512
#define G4 2048
#define SENT 0xFFFFFFFFu

typedef __attribute__((ext_vector_type(8))) short short8;
typedef __attribute__((ext_vector_type(4))) float floatx4;
typedef __attribute__((ext_vector_type(4))) unsigned int uint4v;

__device__ __forceinline__ unsigned short f2bf(float f) {
    unsigned u = __float_as_uint(f);
    return (unsigned short)((u + 0x7FFFu + ((u >> 16) & 1u)) >> 16);
}
__device__ __forceinline__ float bf2f(unsigned short h) {
    return __uint_as_float(((unsigned)h) << 16);
}
__device__ __forceinline__ float sigm(float x) { return 1.f / (1.f + __expf(-x)); }
__device__ __forceinline__ float tanh_f(float x) {
    float e = __expf(-2.f * fabsf(x));
    return copysignf((1.f - e) / (1.f + e), x);
}

// ---------------------------------------------------------------------------
// Kernel A: xz = x @ w + bias, stored fp16. Split-bf16 (x=hi+lo) for accuracy.
// 128x128 tile / block, BK=32 (orig k), K=256. Grid 8192 blocks. (unchanged)
// ---------------------------------------------------------------------------
__global__ __launch_bounds__(256, 2) void lstm_xz(
    const float* __restrict__ x, const float* __restrict__ w,
    const float* __restrict__ bias, _Float16* __restrict__ xzh)
{
    __shared__ unsigned short Ahi[128 * 40];
    __shared__ unsigned short Alo[128 * 40];
    __shared__ unsigned short Wt [128 * 40];

    const int tid = threadIdx.x;
    int idx = blockIdx.x;
    int xcd = idx & 7;
    int chunk = idx >> 3;
    int msup = chunk >> 7;
    int s = chunk & 127;
    int nt = s >> 3;
    int mi0 = s & 7;
    int mt = xcd * 64 + msup * 8 + mi0;
    const int m0 = mt << 7;
    const int n0 = nt << 7;

    const int lane = tid & 63;
    const int wv = tid >> 6;
    const int wm = wv >> 1, wn = wv & 1;
    const int cB = lane & 15, kgrp = lane >> 4;

    floatx4 acc[4][4];
#pragma unroll
    for (int i = 0; i < 4; ++i)
#pragma unroll
        for (int j = 0; j < 4; ++j) acc[i][j] = (floatx4){0.f, 0.f, 0.f, 0.f};

    float bv[4];
#pragma unroll
    for (int ni = 0; ni < 4; ++ni) bv[ni] = bias[n0 + wn * 64 + ni * 16 + cB];

    for (int it = 0; it < 8; ++it) {
        const int k0 = it * 32;
#pragma unroll
        for (int sw = 0; sw < 4; ++sw) {
            int e = sw * 256 + tid;
            int row = e >> 3, kq = e & 7;
            float4 v = *((const float4*)(x + (size_t)(m0 + row) * Ff + k0) + kq);
            unsigned short h0 = f2bf(v.x), h1 = f2bf(v.y), h2 = f2bf(v.z), h3 = f2bf(v.w);
            unsigned short l0 = f2bf(v.x - bf2f(h0)), l1 = f2bf(v.y - bf2f(h1));
            unsigned short l2 = f2bf(v.z - bf2f(h2)), l3 = f2bf(v.w - bf2f(h3));
            uint2 ph, pl;
            ph.x = (unsigned)h0 | ((unsigned)h1 << 16); ph.y = (unsigned)h2 | ((unsigned)h3 << 16);
            pl.x = (unsigned)l0 | ((unsigned)l1 << 16); pl.y = (unsigned)l2 | ((unsigned)l3 << 16);
            *(uint2*)(&Ahi[row * 40 + kq * 4]) = ph;
            *(uint2*)(&Alo[row * 40 + kq * 4]) = pl;
        }
#pragma unroll
        for (int sw = 0; sw < 4; ++sw) {
            int e = sw * 256 + tid;
            int kr = e >> 5, nq = e & 31;
            float4 v = *((const float4*)(w + (size_t)(k0 + kr) * G4 + n0) + nq);
            int nb = nq * 4;
            Wt[(nb + 0) * 40 + kr] = f2bf(v.x);
            Wt[(nb + 1) * 40 + kr] = f2bf(v.y);
            Wt[(nb + 2) * 40 + kr] = f2bf(v.z);
            Wt[(nb + 3) * 40 + kr] = f2bf(v.w);
        }
        __syncthreads();

        short8 bfr[4];
#pragma unroll
        for (int ni = 0; ni < 4; ++ni)
            bfr[ni] = *(const short8*)(&Wt[(wn * 64 + ni * 16 + cB) * 40 + kgrp * 8]);
#pragma unroll
        for (int mi = 0; mi < 4; ++mi) {
            short8 ah = *(const short8*)(&Ahi[(wm * 64 + mi * 16 + cB) * 40 + kgrp * 8]);
            short8 al = *(const short8*)(&Alo[(wm * 64 + mi * 16 + cB) * 40 + kgrp * 8]);
#pragma unroll
            for (int ni = 0; ni < 4; ++ni) {
                acc[mi][ni] = __builtin_amdgcn_mfma_f32_16x16x32_bf16(ah, bfr[ni], acc[mi][ni], 0, 0, 0);
                acc[mi][ni] = __builtin_amdgcn_mfma_f32_16x16x32_bf16(al, bfr[ni], acc[mi][ni], 0, 0, 0);
            }
        }
        __syncthreads();
    }
#pragma unroll
    for (int mi = 0; mi < 4; ++mi)
#pragma unroll
        for (int ni = 0; ni < 4; ++ni) {
            int rowb = m0 + wm * 64 + mi * 16 + kgrp * 4;
            int col = n0 + wn * 64 + ni * 16 + cB;
#pragma unroll
            for (int rr = 0; rr < 4; ++rr)
                xzh[(size_t)(rowb + rr) * G4 + col] = (_Float16)(acc[mi][ni][rr] + bv[ni]);
        }
}

// ---------------------------------------------------------------------------
// Kernel R: persistent scan, 256 blocks = 8 row-groups x 32 col-blocks.
// Block: 128 thr / 2 waves, NO in-loop barriers; wave w owns h cols
// [cb*16 + w*8, +8) (x 4 gates = 32 n). B-frags in registers; A-frags fetched
// directly from the hbuf slot (row-major [16][512] bf16) with per-chunk
// sentinel-retry + incremental MFMA consumption.
// ---------------------------------------------------------------------------
__global__ __launch_bounds__(128, 1) void lstm_rec(
    const _Float16* __restrict__ xzh, const float* __restrict__ rk,
    unsigned* __restrict__ hbuf_u, float* __restrict__ out)
{
    __shared__ unsigned short Rlds[64 * 512];   // 64 KB, staging for B-frag hoist

    const int tid = threadIdx.x;
    const int idx = blockIdx.x;
    const int rg = idx & 7;          // row group
    const int cb = idx >> 3;         // 0..31 col block
    const int b0 = rg * 16;
    const int hc0 = cb * 16;

    const int lane = tid & 63;
    const int wv = tid >> 6;         // 0..1
    const int cB = lane & 15, kgrp = lane >> 4;
    const int c7 = cB & 7;
    const int col = hc0 + wv * 8 + c7;   // this lane's h col (duplicated in lane^8)
    const bool hi = (cB & 8) != 0;

    // ---- preload R slice into LDS, bf16, XOR-swizzled: elem (n,k) at k^((n&7)*8) ----
    // n (0..63): w=n>>5, loc=n&31, gate=((loc>>4)<<1)|((loc>>3)&1), hcol=loc&7
    for (int e = tid; e < 32 * 512; e += 128) {
        int p = e & 31, k = e >> 5;
        int n0 = 2 * p;
        int loc = n0 & 31, w = n0 >> 5;
        int gate = ((loc >> 4) << 1) | ((loc >> 3) & 1);
        int gcol = gate * Hh + hc0 + w * 8 + (loc & 7);
        float2 v = *(const float2*)(rk + (size_t)k * G4 + gcol);
        Rlds[n0 * 512 + (k ^ ((n0 & 7) << 3))] = f2bf(v.x);
        Rlds[(n0 + 1) * 512 + (k ^ (((n0 + 1) & 7) << 3))] = f2bf(v.y);
    }

    // per-row running xz pointers (4), gate offset is an immediate (g*1KB)
    const unsigned* xz_u = (const unsigned*)xzh;
    const unsigned* pr[4];
#pragma unroll
    for (int r = 0; r < 4; ++r)
        pr[r] = xz_u + ((size_t)(b0 + kgrp * 4 + r) * Tt * G4 + (col & ~1)) / 2;

    float xzr[16];                            // [gate*4 + row]
#pragma unroll
    for (int g = 0; g < 4; ++g)
#pragma unroll
        for (int r = 0; r < 4; ++r) {
            unsigned v = pr[r][g * 256];
            xzr[g * 4 + r] = (float)__builtin_bit_cast(_Float16,
                (unsigned short)((col & 1) ? (v >> 16) : (v & 0xffffu)));
        }
#pragma unroll
    for (int r = 0; r < 4; ++r) pr[r] += G4 / 2;   // -> t=1

    __syncthreads();  // Rlds ready (only barrier in the kernel)

    // ---- hoist B fragments to registers: 2 n-tiles x 16 kk = 128 VGPRs ----
    short8 bf0[16], bf1[16];
    {
        const int nb = wv * 32;
        const int swz = c7 << 3;
#pragma unroll
        for (int kk = 0; kk < 16; ++kk) {
            int kb = (kk * 32 + kgrp * 8) ^ swz;
            bf0[kk] = *(const short8*)&Rlds[(nb + cB) * 512 + kb];
            bf1[kk] = *(const short8*)&Rlds[(nb + 16 + cB) * 512 + kb];
        }
    }

    float creg[4] = {0.f, 0.f, 0.f, 0.f};
    unsigned* const gbase = hbuf_u + (size_t)rg * 4 * 4096;   // 4 slots x 16x256 dwords

    for (int t = 0; t < Tt; ++t) {
        const bool last = (t == Tt - 1);

        // 1. prefetch xz(t+1): issued first, latency hides under A-fetch wait
        unsigned pf[16];
        if (!last) {
#pragma unroll
            for (int g = 0; g < 4; ++g)
#pragma unroll
                for (int r = 0; r < 4; ++r)
                    pf[g * 4 + r] = pr[r][g * 256];
        }

        floatx4 acc0 = (floatx4){0.f, 0.f, 0.f, 0.f};
        floatx4 acc1 = (floatx4){0.f, 0.f, 0.f, 0.f};

        if (t > 0) {
            // 2. A-fetch: lane's 16 MFMA A-fragments (row cB, chunk kk = dwords
            //    kk*16 + kgrp*4) from slot (t-1)&3. Issue all 16 once, one vmcnt(0).
            const unsigned* sp = gbase + ((t - 1) & 3) * 4096 + cB * 256 + kgrp * 4;
            uint4v A[16];
#pragma unroll
            for (int kk = 0; kk < 16; ++kk)
                asm volatile("global_load_dwordx4 %0, %1, off offset:%2 sc0 sc1"
                             : "=v"(A[kk]) : "v"(sp), "i"(kk * 64) : "memory");
            asm volatile("s_waitcnt vmcnt(0)" ::: "memory");

            // 3. incremental consumption: per chunk, retry ONLY that 16B until
            //    valid (chunk kk == producer blocks 2kk,2kk+1), then 2 MFMAs.
#pragma unroll
            for (int kk = 0; kk < 16; ++kk) {
                while (__any((A[kk][0] == SENT) | (A[kk][1] == SENT) |
                             (A[kk][2] == SENT) | (A[kk][3] == SENT))) {
                    asm volatile("global_load_dwordx4 %0, %1, off offset:%2 sc0 sc1"
                                 : "=v"(A[kk]) : "v"(sp), "i"(kk * 64) : "memory");
                    asm volatile("s_waitcnt vmcnt(0)" ::: "memory");
                }
                short8 a = __builtin_bit_cast(short8, A[kk]);
                acc0 = __builtin_amdgcn_mfma_f32_16x16x32_bf16(a, bf0[kk], acc0, 0, 0, 0);
                acc1 = __builtin_amdgcn_mfma_f32_16x16x32_bf16(a, bf1[kk], acc1, 0, 0, 0);
            }

            // 4. recycle slot (t-2): wave resets its OWN 8-col slice (16 rows x 4
            //    dwords, 1 dword/lane). Drained by this wave's step-(t+1) vmcnt(0)
            //    before its h(t+1) signal => consumers at t+3 see sentinel.
            if (t >= 2) {
                unsigned* rs = gbase + ((t - 2) & 3) * 4096
                             + (lane >> 2) * 256 + (hc0 >> 1) + wv * 4 + (lane & 3);
                __hip_atomic_store(rs, SENT, __ATOMIC_RELAXED, __HIP_MEMORY_SCOPE_AGENT);
            }
        }
        // t==0: h = 0 -> z = xz only (acc stays 0), no fetch, no GEMM.

        // 5. elementwise, in-register. C layout: col=lane&15, row=kgrp*4+reg.
        float hv[4];
#pragma unroll
        for (int r = 0; r < 4; ++r) {
            float a0 = acc0[r], a1 = acc1[r];
            float a0x = __shfl_xor(a0, 8);
            float a1x = __shfl_xor(a1, 8);
            float zi = (hi ? a0x : a0) + xzr[0 * 4 + r];
            float zf = (hi ? a0 : a0x) + xzr[1 * 4 + r];
            float zg = (hi ? a1x : a1) + xzr[2 * 4 + r];
            float zo = (hi ? a1 : a1x) + xzr[3 * 4 + r];
            creg[r] = sigm(zf) * creg[r] + sigm(zi) * tanh_f(zg);
            hv[r] = sigm(zo) * tanh_f(creg[r]);
        }

        float hn[4];
#pragma unroll
        for (int r = 0; r < 4; ++r) hn[r] = __shfl_xor(hv[r], 1);
        const bool ew = (!hi && !(cB & 1));

        if (!last) {
            // 6. h exchange: fire-and-forget sc1 stores into slot t&3. The data IS
            //    the signal (sentinel-retry on consumer side). No vmcnt, no flag.
            unsigned* wbase = gbase + (t & 3) * 4096;
#pragma unroll
            for (int r = 0; r < 4; ++r) {
                if (ew) {
                    unsigned hp = (unsigned)f2bf(hv[r]) | ((unsigned)f2bf(hn[r]) << 16);
                    __hip_atomic_store(wbase + (kgrp * 4 + r) * 256 + (col >> 1), hp,
                                       __ATOMIC_RELAXED, __HIP_MEMORY_SCOPE_AGENT);
                }
            }
        }

        // 7. output stores (cached; off the producer->consumer chain)
#pragma unroll
        for (int r = 0; r < 4; ++r) {
            if (ew) {
                size_t b = (size_t)(b0 + kgrp * 4 + r);
                *(float2*)(out + (b * Tt + (size_t)t) * Hh + col) = make_float2(hv[r], hn[r]);
            }
        }

        if (last) {
            float* hl = out + (size_t)Bb * Tt * Hh;
            float* cl = hl + (size_t)Bb * Hh;
#pragma unroll
            for (int r = 0; r < 4; ++r) {
                float cn = __shfl_xor(creg[r], 1);
                if (ew) {
                    size_t b = (size_t)(b0 + kgrp * 4 + r);
                    *(float2*)(hl + b * Hh + col) = make_float2(hv[r], hn[r]);
                    *(float2*)(cl + b * Hh + col) = make_float2(creg[r], cn);
                }
            }
            break;
        }

        // 8. consume prefetched xz; advance row pointers
#pragma unroll
        for (int i = 0; i < 16; ++i)
            xzr[i] = (float)__builtin_bit_cast(_Float16,
                (unsigned short)((col & 1) ? (pf[i] >> 16) : (pf[i] & 0xffffu)));
#pragma unroll
        for (int r = 0; r < 4; ++r) pr[r] += G4 / 2;
    }
}

// ---------------------------------------------------------------------------
extern "C" void kernel_launch(void* const* d_in, const int* in_sizes, int n_in,
                              void* d_out, int out_size, void* d_ws, size_t ws_size,
                              hipStream_t stream) {
    (void)in_sizes; (void)n_in; (void)out_size; (void)ws_size;
    const float* x    = (const float*)d_in[0];
    const float* w    = (const float*)d_in[1];
    const float* rk   = (const float*)d_in[2];
    const float* bias = (const float*)d_in[3];
    float* out = (float*)d_out;

    char* ws = (char*)d_ws;
    const size_t XZ_BYTES   = (size_t)Bb * Tt * G4 * sizeof(_Float16);      // 268,435,456
    const size_t HBUF_BYTES = (size_t)8 * 4 * 16 * 256 * 4;                 // 524,288

    _Float16* xzh = (_Float16*)ws;
    unsigned* hbuf = (unsigned*)(ws + XZ_BYTES);

    // sentinel-init all slots (0xFF bytes -> 0xFFFFFFFF dwords)
    hipMemsetAsync(ws + XZ_BYTES, 0xFF, HBUF_BYTES, stream);

    lstm_xz<<<dim3(8192), dim3(256), 0, stream>>>(x, w, bias, xzh);
    lstm_rec<<<dim3(256), dim3(128), 0, stream>>>(xzh, rk, hbuf, out);
}

// Round 6
// 2236.391 us; speedup vs baseline: 2.0134x; 1.9974x over previous
//
#include <hip/hip_runtime.h>
#include <stdint.h>

// LSTM forward, B=128 T=512 F=256 H=512, Keras gate order i,f,g,o.
//  kernel lstm_xz : xz[B*T,2048] = x @ kernel + bias  (split-bf16 MFMA, fp16 output)
//  kernel lstm_rec: persistent scan. R6 = R3 structure (best verified, 1751us) plus:
//    - R4/R5 post-mortem: direct-to-VGPR A-fetch multiplies device-coherent fabric
//      transactions per step (each wave pulls its own scattered copy). REVERTED to
//      block-shared LDS staging (one 16KB copy/block, contiguous 1KB bursts).
//    - PING-PONG h tile in LDS (parity of t) -> ONE __syncthreads per step (the
//      end-of-loop barrier is provably unnecessary: writers of buffer P at t+2 are
//      ordered behind readers of P at t by the t+1 post-stage barrier + poll chain).
//    - h buffers OVERLAY Rlds (dead after B-fragment hoist): LDS 144 -> 128 KB.
//    - Per-row retry: each of the wave's 4 staged rows retries only its own 1KB and
//      ds_writes as soon as valid (was: whole-4KB retry).
//    - Dual accumulator chains (even/odd kk) halve MFMA serial dependency depth.
// ws layout: [0, 256MB) xz fp16 | hbuf 8 groups x 4 slots x 16 rows x 256 dwords (512KB)

#define Bb 128
#define Tt 512
#define Ff 256
#define Hh 512
#define G4 2048
#define SENT 0xFFFFFFFFu

typedef __attribute__((ext_vector_type(8))) short short8;
typedef __attribute__((ext_vector_type(4))) float floatx4;
typedef __attribute__((ext_vector_type(4))) unsigned int uint4v;

__device__ __forceinline__ unsigned short f2bf(float f) {
    unsigned u = __float_as_uint(f);
    return (unsigned short)((u + 0x7FFFu + ((u >> 16) & 1u)) >> 16);
}
__device__ __forceinline__ float bf2f(unsigned short h) {
    return __uint_as_float(((unsigned)h) << 16);
}
__device__ __forceinline__ float sigm(float x) { return 1.f / (1.f + __expf(-x)); }
__device__ __forceinline__ float tanh_f(float x) {
    float e = __expf(-2.f * fabsf(x));
    return copysignf((1.f - e) / (1.f + e), x);
}

// ---------------------------------------------------------------------------
// Kernel A: xz = x @ w + bias, stored fp16. Split-bf16 (x=hi+lo) for accuracy.
// 128x128 tile / block, BK=32 (orig k), K=256. Grid 8192 blocks. (unchanged)
// ---------------------------------------------------------------------------
__global__ __launch_bounds__(256, 2) void lstm_xz(
    const float* __restrict__ x, const float* __restrict__ w,
    const float* __restrict__ bias, _Float16* __restrict__ xzh)
{
    __shared__ unsigned short Ahi[128 * 40];
    __shared__ unsigned short Alo[128 * 40];
    __shared__ unsigned short Wt [128 * 40];

    const int tid = threadIdx.x;
    int idx = blockIdx.x;
    int xcd = idx & 7;
    int chunk = idx >> 3;
    int msup = chunk >> 7;
    int s = chunk & 127;
    int nt = s >> 3;
    int mi0 = s & 7;
    int mt = xcd * 64 + msup * 8 + mi0;
    const int m0 = mt << 7;
    const int n0 = nt << 7;

    const int lane = tid & 63;
    const int wv = tid >> 6;
    const int wm = wv >> 1, wn = wv & 1;
    const int cB = lane & 15, kgrp = lane >> 4;

    floatx4 acc[4][4];
#pragma unroll
    for (int i = 0; i < 4; ++i)
#pragma unroll
        for (int j = 0; j < 4; ++j) acc[i][j] = (floatx4){0.f, 0.f, 0.f, 0.f};

    float bv[4];
#pragma unroll
    for (int ni = 0; ni < 4; ++ni) bv[ni] = bias[n0 + wn * 64 + ni * 16 + cB];

    for (int it = 0; it < 8; ++it) {
        const int k0 = it * 32;
#pragma unroll
        for (int sw = 0; sw < 4; ++sw) {
            int e = sw * 256 + tid;
            int row = e >> 3, kq = e & 7;
            float4 v = *((const float4*)(x + (size_t)(m0 + row) * Ff + k0) + kq);
            unsigned short h0 = f2bf(v.x), h1 = f2bf(v.y), h2 = f2bf(v.z), h3 = f2bf(v.w);
            unsigned short l0 = f2bf(v.x - bf2f(h0)), l1 = f2bf(v.y - bf2f(h1));
            unsigned short l2 = f2bf(v.z - bf2f(h2)), l3 = f2bf(v.w - bf2f(h3));
            uint2 ph, pl;
            ph.x = (unsigned)h0 | ((unsigned)h1 << 16); ph.y = (unsigned)h2 | ((unsigned)h3 << 16);
            pl.x = (unsigned)l0 | ((unsigned)l1 << 16); pl.y = (unsigned)l2 | ((unsigned)l3 << 16);
            *(uint2*)(&Ahi[row * 40 + kq * 4]) = ph;
            *(uint2*)(&Alo[row * 40 + kq * 4]) = pl;
        }
#pragma unroll
        for (int sw = 0; sw < 4; ++sw) {
            int e = sw * 256 + tid;
            int kr = e >> 5, nq = e & 31;
            float4 v = *((const float4*)(w + (size_t)(k0 + kr) * G4 + n0) + nq);
            int nb = nq * 4;
            Wt[(nb + 0) * 40 + kr] = f2bf(v.x);
            Wt[(nb + 1) * 40 + kr] = f2bf(v.y);
            Wt[(nb + 2) * 40 + kr] = f2bf(v.z);
            Wt[(nb + 3) * 40 + kr] = f2bf(v.w);
        }
        __syncthreads();

        short8 bfr[4];
#pragma unroll
        for (int ni = 0; ni < 4; ++ni)
            bfr[ni] = *(const short8*)(&Wt[(wn * 64 + ni * 16 + cB) * 40 + kgrp * 8]);
#pragma unroll
        for (int mi = 0; mi < 4; ++mi) {
            short8 ah = *(const short8*)(&Ahi[(wm * 64 + mi * 16 + cB) * 40 + kgrp * 8]);
            short8 al = *(const short8*)(&Alo[(wm * 64 + mi * 16 + cB) * 40 + kgrp * 8]);
#pragma unroll
            for (int ni = 0; ni < 4; ++ni) {
                acc[mi][ni] = __builtin_amdgcn_mfma_f32_16x16x32_bf16(ah, bfr[ni], acc[mi][ni], 0, 0, 0);
                acc[mi][ni] = __builtin_amdgcn_mfma_f32_16x16x32_bf16(al, bfr[ni], acc[mi][ni], 0, 0, 0);
            }
        }
        __syncthreads();
    }
#pragma unroll
    for (int mi = 0; mi < 4; ++mi)
#pragma unroll
        for (int ni = 0; ni < 4; ++ni) {
            int rowb = m0 + wm * 64 + mi * 16 + kgrp * 4;
            int col = n0 + wn * 64 + ni * 16 + cB;
#pragma unroll
            for (int rr = 0; rr < 4; ++rr)
                xzh[(size_t)(rowb + rr) * G4 + col] = (_Float16)(acc[mi][ni][rr] + bv[ni]);
        }
}

// ---------------------------------------------------------------------------
// Kernel R: persistent scan, 128 blocks = 8 row-groups x 16 col-blocks.
// Block: 256 thr / 4 waves; wave w owns h cols [cb*32 + w*8, +8) (x 4 gates = 32 n).
// B-frags in registers; h tile ping-pong staged in (reused) Rlds; ONE barrier/step.
// ---------------------------------------------------------------------------
__global__ __launch_bounds__(256, 1) void lstm_rec(
    const _Float16* __restrict__ xzh, const float* __restrict__ rk,
    unsigned* __restrict__ hbuf_u, float* __restrict__ out)
{
    __shared__ unsigned short Rlds[128 * 512];   // 128 KB; rows 0-31 reused as h ping-pong

    const int tid = threadIdx.x;
    const int idx = blockIdx.x;
    const int rg = idx & 7;          // row group
    const int cb = idx >> 3;         // 0..15 col block
    const int b0 = rg * 16;
    const int hc0 = cb * 32;

    const int lane = tid & 63;
    const int wv = tid >> 6;
    const int cB = lane & 15, kgrp = lane >> 4;
    const int hcw = hc0 + wv * 8;    // wave's 8 h cols
    const int c7 = cB & 7;
    const int col = hcw + c7;        // this lane's h col (duplicated in lane^8)
    const bool hi = (cB & 8) != 0;

    // ---- preload R slice into LDS, bf16, XOR-swizzled: elem (n,k) at k^((n&7)*8) ----
    for (int e = tid; e < 64 * 512; e += 256) {
        int p = e & 63, k = e >> 6;
        int n0 = 2 * p;
        int loc = n0 & 31, w = n0 >> 5;
        int gate = ((loc >> 4) << 1) | ((loc >> 3) & 1);
        int gcol = gate * Hh + hc0 + w * 8 + (loc & 7);
        float2 v = *(const float2*)(rk + (size_t)k * G4 + gcol);
        Rlds[n0 * 512 + (k ^ ((n0 & 7) << 3))] = f2bf(v.x);
        Rlds[(n0 + 1) * 512 + (k ^ (((n0 + 1) & 7) << 3))] = f2bf(v.y);
    }

    // per-row running xz pointers (4), gate offset is an immediate (g*1KB)
    const unsigned* xz_u = (const unsigned*)xzh;
    const unsigned* pr[4];
#pragma unroll
    for (int r = 0; r < 4; ++r)
        pr[r] = xz_u + ((size_t)(b0 + kgrp * 4 + r) * Tt * G4 + (col & ~1)) / 2;

    float xzr[16];                            // [gate*4 + row]
#pragma unroll
    for (int g = 0; g < 4; ++g)
#pragma unroll
        for (int r = 0; r < 4; ++r) {
            unsigned v = pr[r][g * 256];
            xzr[g * 4 + r] = (float)__builtin_bit_cast(_Float16,
                (unsigned short)((col & 1) ? (v >> 16) : (v & 0xffffu)));
        }
#pragma unroll
    for (int r = 0; r < 4; ++r) pr[r] += G4 / 2;   // -> t=1

    __syncthreads();  // Rlds ready

    // ---- hoist B fragments to registers: 2 n-tiles x 16 kk = 128 VGPRs ----
    short8 bf0[16], bf1[16];
    {
        const int nb = wv * 32;
        const int swz = c7 << 3;
#pragma unroll
        for (int kk = 0; kk < 16; ++kk) {
            int kb = (kk * 32 + kgrp * 8) ^ swz;
            bf0[kk] = *(const short8*)&Rlds[(nb + cB) * 512 + kb];
            bf1[kk] = *(const short8*)&Rlds[(nb + 16 + cB) * 512 + kb];
        }
    }
    __syncthreads();  // hoist reads done; Rlds rows 0-31 now reusable as h buffers

    float creg[4] = {0.f, 0.f, 0.f, 0.f};
    unsigned* const gbase = hbuf_u + (size_t)rg * 4 * 4096;   // 4 slots x 16x256 dwords

    for (int t = 0; t < Tt; ++t) {
        const bool last = (t == Tt - 1);

        // 1. prefetch xz(t+1): HBM latency hides under poll/stage
        unsigned pf[16];
        if (!last) {
#pragma unroll
            for (int g = 0; g < 4; ++g)
#pragma unroll
                for (int r = 0; r < 4; ++r)
                    pf[g * 4 + r] = pr[r][g * 256];
        }

        floatx4 acc0 = (floatx4){0.f, 0.f, 0.f, 0.f};
        floatx4 acc1 = (floatx4){0.f, 0.f, 0.f, 0.f};

        if (t > 0) {
            // ping-pong h buffer for this step (overlaid on Rlds rows 0-31)
            unsigned short* const hs = (t & 1) ? (Rlds + 16 * 512) : Rlds;
            unsigned* const hcu = (unsigned*)hs;

            // 2. poll+stage h(t-1) from slot (t-1)&3: wave stages rows wv+4s.
            //    Issue all 4 row-loads once; then per ROW retry only that 1KB until
            //    no sentinel, ds_write it immediately (swizzled at 4-dword chunks).
            {
                const unsigned* sb = gbase + ((t - 1) & 3) * 4096;
                const unsigned* q0 = sb + (wv + 0) * 256 + 4 * lane;
                const unsigned* q1 = sb + (wv + 4) * 256 + 4 * lane;
                const unsigned* q2 = sb + (wv + 8) * 256 + 4 * lane;
                const unsigned* q3 = sb + (wv + 12) * 256 + 4 * lane;
                uint4v v0, v1, v2, v3;
                asm volatile("global_load_dwordx4 %0, %1, off sc0 sc1" : "=v"(v0) : "v"(q0) : "memory");
                asm volatile("global_load_dwordx4 %0, %1, off sc0 sc1" : "=v"(v1) : "v"(q1) : "memory");
                asm volatile("global_load_dwordx4 %0, %1, off sc0 sc1" : "=v"(v2) : "v"(q2) : "memory");
                asm volatile("global_load_dwordx4 %0, %1, off sc0 sc1" : "=v"(v3) : "v"(q3) : "memory");
                asm volatile("s_waitcnt vmcnt(0)" ::: "memory");
                while (__any((v0[0] == SENT) | (v0[1] == SENT) | (v0[2] == SENT) | (v0[3] == SENT))) {
                    asm volatile("global_load_dwordx4 %0, %1, off sc0 sc1" : "=v"(v0) : "v"(q0) : "memory");
                    asm volatile("s_waitcnt vmcnt(0)" ::: "memory");
                }
                *(uint4v*)(hcu + (wv + 0) * 256 + 4 * (lane ^ ((wv + 0) & 7))) = v0;
                while (__any((v1[0] == SENT) | (v1[1] == SENT) | (v1[2] == SENT) | (v1[3] == SENT))) {
                    asm volatile("global_load_dwordx4 %0, %1, off sc0 sc1" : "=v"(v1) : "v"(q1) : "memory");
                    asm volatile("s_waitcnt vmcnt(0)" ::: "memory");
                }
                *(uint4v*)(hcu + (wv + 4) * 256 + 4 * (lane ^ ((wv + 4) & 7))) = v1;
                while (__any((v2[0] == SENT) | (v2[1] == SENT) | (v2[2] == SENT) | (v2[3] == SENT))) {
                    asm volatile("global_load_dwordx4 %0, %1, off sc0 sc1" : "=v"(v2) : "v"(q2) : "memory");
                    asm volatile("s_waitcnt vmcnt(0)" ::: "memory");
                }
                *(uint4v*)(hcu + (wv + 8) * 256 + 4 * (lane ^ ((wv + 8) & 7))) = v2;
                while (__any((v3[0] == SENT) | (v3[1] == SENT) | (v3[2] == SENT) | (v3[3] == SENT))) {
                    asm volatile("global_load_dwordx4 %0, %1, off sc0 sc1" : "=v"(v3) : "v"(q3) : "memory");
                    asm volatile("s_waitcnt vmcnt(0)" ::: "memory");
                }
                *(uint4v*)(hcu + (wv + 12) * 256 + 4 * (lane ^ ((wv + 12) & 7))) = v3;
            }

            // 3. recycle slot (t-2): re-sentinel own 32-col region (fire-and-forget;
            //    drained by this wave's next poll vmcnt(0), before h(t+1) signal).
            if (t >= 2) {
                unsigned* rs = gbase + ((t - 2) & 3) * 4096
                             + (tid >> 4) * 256 + (hc0 >> 1) + (tid & 15);
                __hip_atomic_store(rs, SENT, __ATOMIC_RELAXED, __HIP_MEMORY_SCOPE_AGENT);
            }

            __syncthreads();   // the ONLY per-step barrier: staged tile visible to all

            // 4. GEMM: 16 ds_read_b128 (A) + 32 MFMA, B in registers.
            //    Dual accumulator chains (even/odd kk) halve serial MFMA depth.
            floatx4 e0 = (floatx4){0.f, 0.f, 0.f, 0.f};
            floatx4 e1 = (floatx4){0.f, 0.f, 0.f, 0.f};
            const int swz = c7 << 3;
#pragma unroll
            for (int kk = 0; kk < 16; kk += 2) {
                int kb0 = (kk * 32 + kgrp * 8) ^ swz;
                int kb1 = ((kk + 1) * 32 + kgrp * 8) ^ swz;
                short8 a0 = *(const short8*)&hs[cB * 512 + kb0];
                short8 a1 = *(const short8*)&hs[cB * 512 + kb1];
                acc0 = __builtin_amdgcn_mfma_f32_16x16x32_bf16(a0, bf0[kk], acc0, 0, 0, 0);
                acc1 = __builtin_amdgcn_mfma_f32_16x16x32_bf16(a0, bf1[kk], acc1, 0, 0, 0);
                e0 = __builtin_amdgcn_mfma_f32_16x16x32_bf16(a1, bf0[kk + 1], e0, 0, 0, 0);
                e1 = __builtin_amdgcn_mfma_f32_16x16x32_bf16(a1, bf1[kk + 1], e1, 0, 0, 0);
            }
            acc0 = acc0 + e0;
            acc1 = acc1 + e1;
        }
        // t==0: h = 0 -> z = xz only (acc stays 0), no stage, no GEMM.

        // 5. elementwise, in-register. C layout: col=lane&15, row=kgrp*4+reg.
        float hv[4];
#pragma unroll
        for (int r = 0; r < 4; ++r) {
            float a0 = acc0[r], a1 = acc1[r];
            float a0x = __shfl_xor(a0, 8);
            float a1x = __shfl_xor(a1, 8);
            float zi = (hi ? a0x : a0) + xzr[0 * 4 + r];
            float zf = (hi ? a0 : a0x) + xzr[1 * 4 + r];
            float zg = (hi ? a1x : a1) + xzr[2 * 4 + r];
            float zo = (hi ? a1 : a1x) + xzr[3 * 4 + r];
            creg[r] = sigm(zf) * creg[r] + sigm(zi) * tanh_f(zg);
            hv[r] = sigm(zo) * tanh_f(creg[r]);
        }

        float hn[4];
#pragma unroll
        for (int r = 0; r < 4; ++r) hn[r] = __shfl_xor(hv[r], 1);
        const bool ew = (!hi && !(cB & 1));

        if (!last) {
            // 6. h exchange: fire-and-forget sc1 stores into slot t&3. The data IS
            //    the signal (sentinel-poll on consumer side). No vmcnt, no flag.
            unsigned* wbase = gbase + (t & 3) * 4096;
#pragma unroll
            for (int r = 0; r < 4; ++r) {
                if (ew) {
                    unsigned hp = (unsigned)f2bf(hv[r]) | ((unsigned)f2bf(hn[r]) << 16);
                    __hip_atomic_store(wbase + (kgrp * 4 + r) * 256 + (col >> 1), hp,
                                       __ATOMIC_RELAXED, __HIP_MEMORY_SCOPE_AGENT);
                }
            }
        }

        // 7. output stores (cached; off the producer->consumer chain)
#pragma unroll
        for (int r = 0; r < 4; ++r) {
            if (ew) {
                size_t b = (size_t)(b0 + kgrp * 4 + r);
                *(float2*)(out + (b * Tt + (size_t)t) * Hh + col) = make_float2(hv[r], hn[r]);
            }
        }

        if (last) {
            float* hl = out + (size_t)Bb * Tt * Hh;
            float* cl = hl + (size_t)Bb * Hh;
#pragma unroll
            for (int r = 0; r < 4; ++r) {
                float cn = __shfl_xor(creg[r], 1);
                if (ew) {
                    size_t b = (size_t)(b0 + kgrp * 4 + r);
                    *(float2*)(hl + b * Hh + col) = make_float2(hv[r], hn[r]);
                    *(float2*)(cl + b * Hh + col) = make_float2(creg[r], cn);
                }
            }
            break;
        }

        // 8. consume prefetched xz; advance row pointers. No barrier here:
        //    next step writes the OTHER h buffer (ping-pong), and its writers are
        //    ordered behind this step's readers via the t+1 poll->stage->barrier.
#pragma unroll
        for (int i = 0; i < 16; ++i)
            xzr[i] = (float)__builtin_bit_cast(_Float16,
                (unsigned short)((col & 1) ? (pf[i] >> 16) : (pf[i] & 0xffffu)));
#pragma unroll
        for (int r = 0; r < 4; ++r) pr[r] += G4 / 2;
    }
}

// ---------------------------------------------------------------------------
extern "C" void kernel_launch(void* const* d_in, const int* in_sizes, int n_in,
                              void* d_out, int out_size, void* d_ws, size_t ws_size,
                              hipStream_t stream) {
    (void)in_sizes; (void)n_in; (void)out_size; (void)ws_size;
    const float* x    = (const float*)d_in[0];
    const float* w    = (const float*)d_in[1];
    const float* rk   = (const float*)d_in[2];
    const float* bias = (const float*)d_in[3];
    float* out = (float*)d_out;

    char* ws = (char*)d_ws;
    const size_t XZ_BYTES   = (size_t)Bb * Tt * G4 * sizeof(_Float16);      // 268,435,456
    const size_t HBUF_BYTES = (size_t)8 * 4 * 16 * 256 * 4;                 // 524,288

    _Float16* xzh = (_Float16*)ws;
    unsigned* hbuf = (unsigned*)(ws + XZ_BYTES);

    // sentinel-init all slots (0xFF bytes -> 0xFFFFFFFF dwords)
    hipMemsetAsync(ws + XZ_BYTES, 0xFF, HBUF_BYTES, stream);

    lstm_xz<<<dim3(8192), dim3(256), 0, stream>>>(x, w, bias, xzh);
    lstm_rec<<<dim3(128), dim3(256), 0, stream>>>(xzh, rk, hbuf, out);
}